// Round 9
// baseline (515.614 us; speedup 1.0000x reference)
//
#include <hip/hip_runtime.h>

#define DIM 32
#define BLOCK 256
#define T 4       // tiles (64 rows) per wave; block = 4 waves * 256 rows; grid = 1024

// ---------------------------------------------------------------------------
// The full Gibbs sweep is affine: out = A*x + B*n + c, with
//   A = E31*...*E0,  E_i = I with row i replaced by c_i (c_ii = 0, c_ij = -P_ij/P_ii)
//   B[:,i] = s_i * (E31*...*E_{i+1}) e_i   (lower-tri incl diag, s_i = sqrt(1/P_ii))
//   c = sum_i m_i * (E31*...*E_{i+1}) e_i
// ws layout: A[1024] col-major | B[1024] col-major | c[32]  (2080 floats)
// Verified correct in rounds 7-8 (passed, absmax = baseline).
// ---------------------------------------------------------------------------
__global__ __launch_bounds__(1024) void gibbs_setup_kernel(
    const float* __restrict__ prec,
    const float* __restrict__ mu,
    float* __restrict__ ws)
{
    const int tid = threadIdx.x;
    const int k = tid >> 5;   // row of S
    const int j = tid & 31;   // col of S
    __shared__ float S[32][33];
    __shared__ float cm[32][33];
    __shared__ float coli[32];
    __shared__ float sv[32], mv[32], cacc[32];

    {
        const float pii = prec[k * DIM + k];
        cm[k][j] = (j == k) ? 0.0f : (-prec[k * DIM + j] / pii);
        S[k][j] = (j == k) ? 1.0f : 0.0f;
        if (j == 0) {
            sv[k] = sqrtf(1.0f / pii);
            mv[k] = mu[k];
            cacc[k] = 0.0f;
        }
    }
    __syncthreads();

    for (int i = 31; i >= 0; --i) {
        if (j == 0) {
            const float ski = S[k][i];
            coli[k] = ski;                         // stash old col i
            ws[1024 + i * 32 + k] = sv[i] * ski;   // B col-major
            cacc[k] += mv[i] * ski;
        }
        __syncthreads();
        S[k][j] += coli[k] * (cm[i][j] - ((j == i) ? 1.0f : 0.0f));
        __syncthreads();
    }
    ws[j * 32 + k] = S[k][j];                      // A col-major
    if (j == 0) ws[2048 + k] = cacc[k];
}

// ---------------------------------------------------------------------------
// Sweep: 1 row/lane, NO LDS. x and n stream per-lane through depth-3 rotating
// register pipes (12 VGPR each; landing pad = 4 regs, never 32 -> no spill,
// the R4/R7 killer). Work = 32 uniform "pairs" (A-col-quad j + B-col-quad j,
// ~190 cyc each); pair p consumes slot p%3, refills it with stream quad p+3
// (~570 cyc lead), crossing tile boundaries seamlessly (T=4, fully unrolled,
// all pipe indices compile-time). Phase convoy eliminated: every pair issues
// 2 loads -> memory demand is uniform in time, not burst-then-idle.
// ---------------------------------------------------------------------------
__global__ __launch_bounds__(BLOCK) void gibbs_sweep_kernel(
    const float* __restrict__ x,
    const float* __restrict__ noise,
    const float* __restrict__ ws,
    float* __restrict__ out)
{
    const float* __restrict__ Acm = ws;          // Acm[j*32+k] = A[k][j]
    const float* __restrict__ Bcm = ws + 1024;   // Bcm[j*32+k] = B[k][j], lower-tri
    const float* __restrict__ cv  = ws + 2048;

    const int wid  = threadIdx.x >> 6;
    const int lane = threadIdx.x & 63;
    const long w = (long)blockIdx.x * 4 + wid;   // global wave id
    const long lrow = w * (T * 64) + lane;       // lane's row in its wave's tile 0

    // per-lane streams: tile i, quad q  ->  [i*512 + q]  (64-row tile = 512 float4)
    const float4* __restrict__ xr = (const float4*)(x     + lrow * DIM);
    const float4* __restrict__ nr = (const float4*)(noise + lrow * DIM);
    float4*       __restrict__ og = (float4*)(out + lrow * DIM);

    // depth-3 rotating pipes; all indices compile-time (rule #20)
    float4 xq[3], nq[3];
#pragma unroll
    for (int s = 0; s < 3; ++s) { xq[s] = xr[s]; nq[s] = nr[s]; }

#pragma unroll
    for (int i = 0; i < T; ++i) {
        float acc[DIM];
#pragma unroll
        for (int k = 0; k < DIM; ++k) acc[k] = cv[k];

#pragma unroll
        for (int j = 0; j < 8; ++j) {
            const int p = i * 8 + j;          // global pair index 0..31
            const float4 qx = xq[p % 3];
            const float4 qn = nq[p % 3];
            if (p + 3 < T * 8) {              // refill freed slot with quad p+3
                const int np = p + 3;
                xq[p % 3] = xr[(np >> 3) * 512 + (np & 7)];
                nq[p % 3] = nr[(np >> 3) * 512 + (np & 7)];
            }
            const float xs[4] = {qx.x, qx.y, qx.z, qx.w};
            const float ns[4] = {qn.x, qn.y, qn.z, qn.w};
            // A columns 4j..4j+3 (dense)
#pragma unroll
            for (int tt = 0; tt < 4; ++tt) {
                const float* __restrict__ aj = Acm + (j * 4 + tt) * 32;
#pragma unroll
                for (int k = 0; k < 32; ++k) acc[k] = fmaf(xs[tt], aj[k], acc[k]);
            }
            // B columns 4j..4j+3 (lower-tri: k >= col)
#pragma unroll
            for (int tt = 0; tt < 4; ++tt) {
                const int col = j * 4 + tt;
                const float* __restrict__ bj = Bcm + col * 32;
#pragma unroll
                for (int k = col; k < 32; ++k) acc[k] = fmaf(ns[tt], bj[k], acc[k]);
            }
            __builtin_amdgcn_sched_barrier(0);   // pin pipe refills to their pair
        }

        // stores: strided per-lane direct from acc (R0/R8-proven clean traffic)
#pragma unroll
        for (int kk = 0; kk < 8; ++kk)
            og[i * 512 + kk] = make_float4(acc[kk * 4], acc[kk * 4 + 1],
                                           acc[kk * 4 + 2], acc[kk * 4 + 3]);
        __builtin_amdgcn_sched_barrier(0);
    }
}

extern "C" void kernel_launch(void* const* d_in, const int* in_sizes, int n_in,
                              void* d_out, int out_size, void* d_ws, size_t ws_size,
                              hipStream_t stream) {
    const float* x     = (const float*)d_in[0];  // (B, 32)
    const float* noise = (const float*)d_in[1];  // (B, 32)
    const float* prec  = (const float*)d_in[2];  // (32, 32)
    const float* mu    = (const float*)d_in[3];  // (32,)
    float* out = (float*)d_out;
    float* ws  = (float*)d_ws;                   // needs 2080 floats (8.3 KB)

    const int B = in_sizes[0] / DIM;             // 1048576
    const int grid = B / (BLOCK * T);            // 1024 blocks

    gibbs_setup_kernel<<<1, 1024, 0, stream>>>(prec, mu, ws);
    gibbs_sweep_kernel<<<grid, BLOCK, 0, stream>>>(x, noise, ws, out);
}